// Round 1
// baseline (250.683 us; speedup 1.0000x reference)
//
#include <hip/hip_runtime.h>
#include <hip/hip_bf16.h>

// z[e, :] = h[src[e], :] * h[dst[e], :]
// h: [50000, 64] f32, src/dst: [800000] int, out: [800000, 64] f32
//
// Layout: 16 threads per edge, each thread handles one float4 (16 B) of the
// 64-float row. Reads of h rows are gathers but h (12.8 MB) is L2/L3-resident;
// the output write (204.8 MB) is the HBM-bound term.

#define D_FEAT 64
#define CHUNKS_PER_EDGE 16   // 64 floats / 4 per float4

__global__ __launch_bounds__(256) void hadamard_gather_kernel(
    const float* __restrict__ h,
    const int* __restrict__ src,
    const int* __restrict__ dst,
    float* __restrict__ out,
    int n_edges)
{
    int tid = blockIdx.x * blockDim.x + threadIdx.x;
    int e = tid >> 4;        // edge index
    int c = tid & 15;        // float4 chunk within the row
    if (e >= n_edges) return;

    long long s = src[e];
    long long d = dst[e];

    const float4* hs = reinterpret_cast<const float4*>(h + s * D_FEAT) + c;
    const float4* hd = reinterpret_cast<const float4*>(h + d * D_FEAT) + c;
    float4 a = *hs;
    float4 b = *hd;

    float4 r;
    r.x = a.x * b.x;
    r.y = a.y * b.y;
    r.z = a.z * b.z;
    r.w = a.w * b.w;

    reinterpret_cast<float4*>(out + (long long)e * D_FEAT)[c] = r;
}

extern "C" void kernel_launch(void* const* d_in, const int* in_sizes, int n_in,
                              void* d_out, int out_size, void* d_ws, size_t ws_size,
                              hipStream_t stream) {
    const float* h   = reinterpret_cast<const float*>(d_in[0]);
    const int*   src = reinterpret_cast<const int*>(d_in[1]);
    const int*   dst = reinterpret_cast<const int*>(d_in[2]);
    float* out = reinterpret_cast<float*>(d_out);

    int n_edges = in_sizes[1];   // 800000
    int total_threads = n_edges * CHUNKS_PER_EDGE;
    int block = 256;
    int grid = (total_threads + block - 1) / block;

    hadamard_gather_kernel<<<grid, block, 0, stream>>>(h, src, dst, out, n_edges);
}